// Round 10
// baseline (175.246 us; speedup 1.0000x reference)
//
#include <hip/hip_runtime.h>
#include <math.h>

// z = (64,64,64,64) fp32 -> 262144 vectors of dim 64; codebook = 1024 x 64 fp32.
constexpr int DIM  = 64;
constexpr int KCB  = 1024;
constexpr int NVEC = 262144;
constexpr long long NELEM = 16777216LL;
constexpr int WAVES   = 16;              // 1024 threads/block
constexpr int TILES   = 4;               // 64 rows/wave
constexpr int ROWS_PB = WAVES * TILES * 16;          // 1024 rows/block
constexpr int GRID    = NVEC / ROWS_PB;  // 256 blocks = 1 per CU

typedef short bf16x8 __attribute__((ext_vector_type(8)));  // 8 bf16 = 4 VGPRs
typedef float f32x4  __attribute__((ext_vector_type(4)));
typedef float fvec4  __attribute__((ext_vector_type(4)));  // nontemporal ld/st

// fp32 -> bf16 round-to-nearest-even, result in low 16 bits
__device__ __forceinline__ unsigned f2bfu(float f) {
    union { float f; unsigned u; } v; v.f = f;
    return (v.u + 0x7fffu + ((v.u >> 16) & 1u)) >> 16;
}

// (u & 0xFFFFFC00) | cv in ONE VALU op.
__device__ __forceinline__ float pack_dc(unsigned u, unsigned cv, unsigned msk) {
    unsigned r;
    asm("v_bfi_b32 %0, %1, %2, %3" : "=v"(r) : "v"(msk), "v"(u), "v"(cv));
    return __uint_as_float(r);
}

// Single dispatch, one block per CU, ONE barrier. Whole codebook in LDS as
// bf16(-2*cb), XOR-swizzled. 16 waves x 64 rows + 2-deep B-prefetch +
// in-bundle lag-consume (r9 structure).
// KEY r10 change: amdgpu_waves_per_eu(4,4). r9's launch_bounds(1024,4) sets
// only a MIN waves/EU; the allocator then targeted 8 waves/EU (64-VGPR step)
// even though 136 KB LDS already caps the CU at 4 waves/EU -> it spilled
// ~50 MB of scratch (WRITE 65.6->116.8 MB, VGPR stuck at 64). Pinning
// min=max=4 makes the 128-VGPR budget actually usable.
// Loss from the tracked packed min: ||z-e||^2 = ||z||^2 + (||e||^2 - 2<e,z>).
__global__ __launch_bounds__(1024) __attribute__((amdgpu_waves_per_eu(4, 4)))
void vq_fused(
        const float* __restrict__ z,
        const float* __restrict__ cb,
        float* __restrict__ out,
        float* __restrict__ ws) {

    __shared__ unsigned sB[KCB * 32];       // 128 KB swizzled bf16(-2*cb)
    __shared__ float    s_esq[KCB];         // 4 KB ||e_k||^2
    __shared__ int      s_idx[WAVES * 64];  // 4 KB per-wave argmin exchange
    __shared__ float    s_red[WAVES];       // block loss partials

    const int tid  = threadIdx.x;
    const int lane = tid & 63;
    const int wave = tid >> 6;
    const int quad = lane >> 4;
    const int lrow = lane & 15;
    const int r0   = blockIdx.x * ROWS_PB + wave * (TILES * 16);

    // ---- A fragments FIRST (cold per-block read; latency hides under cb
    //      staging). A[m=lrow][k=quad*8+j], bf16(z); exact fp32 ||z||^2. ----
    bf16x8 a0[TILES], a1[TILES];
    float zsq = 0.f;
    #pragma unroll
    for (int t = 0; t < TILES; ++t) {
        const fvec4* zr = (const fvec4*)(z + (size_t)(r0 + t * 16 + lrow) * DIM + quad * 8);
        fvec4 p0 = __builtin_nontemporal_load(zr);
        fvec4 p1 = __builtin_nontemporal_load(zr + 1);
        fvec4 p2 = __builtin_nontemporal_load(zr + 8);
        fvec4 p3 = __builtin_nontemporal_load(zr + 9);
        zsq = fmaf(p0[0], p0[0], zsq); zsq = fmaf(p0[1], p0[1], zsq);
        zsq = fmaf(p0[2], p0[2], zsq); zsq = fmaf(p0[3], p0[3], zsq);
        zsq = fmaf(p1[0], p1[0], zsq); zsq = fmaf(p1[1], p1[1], zsq);
        zsq = fmaf(p1[2], p1[2], zsq); zsq = fmaf(p1[3], p1[3], zsq);
        zsq = fmaf(p2[0], p2[0], zsq); zsq = fmaf(p2[1], p2[1], zsq);
        zsq = fmaf(p2[2], p2[2], zsq); zsq = fmaf(p2[3], p2[3], zsq);
        zsq = fmaf(p3[0], p3[0], zsq); zsq = fmaf(p3[1], p3[1], zsq);
        zsq = fmaf(p3[2], p3[2], zsq); zsq = fmaf(p3[3], p3[3], zsq);
        a0[t][0] = (short)f2bfu(p0[0]); a0[t][1] = (short)f2bfu(p0[1]);
        a0[t][2] = (short)f2bfu(p0[2]); a0[t][3] = (short)f2bfu(p0[3]);
        a0[t][4] = (short)f2bfu(p1[0]); a0[t][5] = (short)f2bfu(p1[1]);
        a0[t][6] = (short)f2bfu(p1[2]); a0[t][7] = (short)f2bfu(p1[3]);
        a1[t][0] = (short)f2bfu(p2[0]); a1[t][1] = (short)f2bfu(p2[1]);
        a1[t][2] = (short)f2bfu(p2[2]); a1[t][3] = (short)f2bfu(p2[3]);
        a1[t][4] = (short)f2bfu(p3[0]); a1[t][5] = (short)f2bfu(p3[1]);
        a1[t][6] = (short)f2bfu(p3[2]); a1[t][7] = (short)f2bfu(p3[3]);
    }

    // ---- build B in LDS (swizzled) + esq from fp32 cb (1024 thr x 8 chunks).
    //      slot s = c*1024+tid; col=s>>3, jj=tid&7, part=(jj-col)&7;
    //      8 consecutive lanes hold the 8 parts of one codeword. ----
    {
        const int col_l = tid >> 3;            // 0..127 within chunk
        const int jj    = tid & 7;
        const int part  = (jj - col_l) & 7;
        const float* src = cb + col_l * DIM + part * 8;
        char* dst = (char*)sB + tid * 16;
        #pragma unroll
        for (int c = 0; c < 8; ++c) {          // chunk c: codewords c*128..
            float4 v0 = *(const float4*)(src + c * 8192);
            float4 v1 = *(const float4*)(src + c * 8192 + 4);
            float es = v0.x * v0.x;
            es = fmaf(v0.y, v0.y, es);
            es = fmaf(v0.z, v0.z, es);
            es = fmaf(v0.w, v0.w, es);
            es = fmaf(v1.x, v1.x, es);
            es = fmaf(v1.y, v1.y, es);
            es = fmaf(v1.z, v1.z, es);
            es = fmaf(v1.w, v1.w, es);
            es += __shfl_xor(es, 1, 64);
            es += __shfl_xor(es, 2, 64);
            es += __shfl_xor(es, 4, 64);
            if (jj == 0) s_esq[c * 128 + col_l] = es;
            uint4 w;
            w.x = f2bfu(-2.f * v0.x) | (f2bfu(-2.f * v0.y) << 16);
            w.y = f2bfu(-2.f * v0.z) | (f2bfu(-2.f * v0.w) << 16);
            w.z = f2bfu(-2.f * v1.x) | (f2bfu(-2.f * v1.y) << 16);
            w.w = f2bfu(-2.f * v1.z) | (f2bfu(-2.f * v1.w) << 16);
            *(uint4*)(dst + c * 16384) = w;
        }
    }

    __syncthreads();   // the ONLY staging barrier; waves free-run after this

    const int pos0 = ((quad + lrow) & 7) * 4;       // b0: part=quad   (K 0..31)
    const int pos1 = ((quad + 4 + lrow) & 7) * 4;   // b1: part=quad+4 (K 32..63)
    const int base = lrow * 32;
    const unsigned msk = 0xFFFFFC00u;

    float best[TILES][4];
    #pragma unroll
    for (int t = 0; t < TILES; ++t)
        #pragma unroll
        for (int i = 0; i < 4; ++i) best[t][i] = INFINITY;

    // Bundle jj (0..31) covers codeword groups rows 32jj+lrow and +16.
#define LOADB(B0A, B1A, B0B, B1B, JJ) do {                                   \
        const unsigned* bp_ = sB + (JJ) * 1024 + base;                       \
        B0A = *(const bf16x8*)(bp_ + pos0);                                  \
        B1A = *(const bf16x8*)(bp_ + pos1);                                  \
        B0B = *(const bf16x8*)(bp_ + 512 + pos0);                            \
        B1B = *(const bf16x8*)(bp_ + 512 + pos1);                            \
    } while (0)
#define LOADE(EA, EB, JJ) do {                                               \
        EA = s_esq[(JJ) * 32 + lrow];                                        \
        EB = s_esq[(JJ) * 32 + 16 + lrow];                                   \
    } while (0)
#define CONS(ACCA, ACCB, T, CVA, CVB) do {                                   \
        _Pragma("unroll")                                                    \
        for (int i_ = 0; i_ < 4; ++i_) {                                     \
            float pkA = pack_dc(__float_as_uint(ACCA[T][i_]), CVA, msk);     \
            float pkB = pack_dc(__float_as_uint(ACCB[T][i_]), CVB, msk);     \
            best[T][i_] = fminf(best[T][i_], fminf(pkA, pkB));               \
        } } while (0)
#define BODY(B0A, B1A, B0B, B1B, EA, EB, JJ) do {                            \
        const unsigned cvA = (unsigned)((JJ) * 32 + lrow);                   \
        const unsigned cvB = cvA + 16u;                                      \
        const f32x4 esvA = { EA, EA, EA, EA };                               \
        const f32x4 esvB = { EB, EB, EB, EB };                               \
        f32x4 accA[TILES], accB[TILES];                                      \
        __builtin_amdgcn_s_setprio(1);                                       \
        accA[0] = __builtin_amdgcn_mfma_f32_16x16x32_bf16(a1[0], B1A,        \
                  __builtin_amdgcn_mfma_f32_16x16x32_bf16(a0[0], B0A, esvA, 0,0,0), 0,0,0); \
        accB[0] = __builtin_amdgcn_mfma_f32_16x16x32_bf16(a1[0], B1B,        \
                  __builtin_amdgcn_mfma_f32_16x16x32_bf16(a0[0], B0B, esvB, 0,0,0), 0,0,0); \
        accA[1] = __builtin_amdgcn_mfma_f32_16x16x32_bf16(a1[1], B1A,        \
                  __builtin_amdgcn_mfma_f32_16x16x32_bf16(a0[1], B0A, esvA, 0,0,0), 0,0,0); \
        accB[1] = __builtin_amdgcn_mfma_f32_16x16x32_bf16(a1[1], B1B,        \
                  __builtin_amdgcn_mfma_f32_16x16x32_bf16(a0[1], B0B, esvB, 0,0,0), 0,0,0); \
        CONS(accA, accB, 0, cvA, cvB);                                       \
        accA[2] = __builtin_amdgcn_mfma_f32_16x16x32_bf16(a1[2], B1A,        \
                  __builtin_amdgcn_mfma_f32_16x16x32_bf16(a0[2], B0A, esvA, 0,0,0), 0,0,0); \
        accB[2] = __builtin_amdgcn_mfma_f32_16x16x32_bf16(a1[2], B1B,        \
                  __builtin_amdgcn_mfma_f32_16x16x32_bf16(a0[2], B0B, esvB, 0,0,0), 0,0,0); \
        CONS(accA, accB, 1, cvA, cvB);                                       \
        accA[3] = __builtin_amdgcn_mfma_f32_16x16x32_bf16(a1[3], B1A,        \
                  __builtin_amdgcn_mfma_f32_16x16x32_bf16(a0[3], B0A, esvA, 0,0,0), 0,0,0); \
        accB[3] = __builtin_amdgcn_mfma_f32_16x16x32_bf16(a1[3], B1B,        \
                  __builtin_amdgcn_mfma_f32_16x16x32_bf16(a0[3], B0B, esvB, 0,0,0), 0,0,0); \
        CONS(accA, accB, 2, cvA, cvB);                                       \
        __builtin_amdgcn_s_setprio(0);                                       \
        CONS(accA, accB, 3, cvA, cvB);                                       \
    } while (0)

    // ---- software-pipelined scan: prefetch bundle j+1 before computing j ----
    bf16x8 b0A_e, b1A_e, b0B_e, b1B_e, b0A_o, b1A_o, b0B_o, b1B_o;
    float  esA_e, esB_e, esA_o, esB_o;
    LOADB(b0A_e, b1A_e, b0B_e, b1B_e, 0);
    LOADE(esA_e, esB_e, 0);
    for (int j = 0; j < 32; j += 2) {
        LOADB(b0A_o, b1A_o, b0B_o, b1B_o, j + 1);      // prefetch odd
        LOADE(esA_o, esB_o, j + 1);
        BODY(b0A_e, b1A_e, b0B_e, b1B_e, esA_e, esB_e, j);
        const int j2 = (j + 2) & 31;                   // clamp; j=30 dummy
        LOADB(b0A_e, b1A_e, b0B_e, b1B_e, j2);         // prefetch even
        LOADE(esA_e, esB_e, j2);
        BODY(b0A_o, b1A_o, b0B_o, b1B_o, esA_o, esB_o, j + 1);
    }
#undef BODY
#undef CONS
#undef LOADE
#undef LOADB

    // ---- min across the 16-lane col group (butterfly) ----
    #pragma unroll
    for (int t = 0; t < TILES; ++t)
        #pragma unroll
        for (int i = 0; i < 4; ++i) {
            float bs = best[t][i];
            bs = fminf(bs, __shfl_xor(bs, 1, 64));
            bs = fminf(bs, __shfl_xor(bs, 2, 64));
            bs = fminf(bs, __shfl_xor(bs, 4, 64));
            bs = fminf(bs, __shfl_xor(bs, 8, 64));
            best[t][i] = bs;
        }

    // lane lrow owns (t=lrow>>2, i=lrow&3) -> row t*16 + quad*4 + i.
    // Static selection only (rule #20); all 16 lanes own exactly one row.
    float mypk = best[0][0];
    #pragma unroll
    for (int t = 0; t < TILES; ++t)
        #pragma unroll
        for (int i = 0; i < 4; ++i)
            if (lrow == t * 4 + i) mypk = best[t][i];

    const unsigned ub = __float_as_uint(mypk);
    s_idx[wave * 64 + (lrow >> 2) * 16 + quad * 4 + (lrow & 3)] =
        (int)(ub & 0x3FFu);
    // loss: ||z||^2 partial + (||e||^2 - 2<e,z>) of the owned row
    float lsum = zsq + __uint_as_float(ub & msk);

    // wave-local LDS exchange: same wave writes then reads; fence lgkm only.
    asm volatile("s_waitcnt lgkmcnt(0)" ::: "memory");

    // ---- epilogue: gather exact fp32 codebook rows, coalesced nt store ----
    const fvec4* cb4 = (const fvec4*)cb;
    fvec4* out4 = (fvec4*)out;
    #pragma unroll 4
    for (int g = 0; g < 16; ++g) {
        const int rr = g * 4 + quad;                 // 4 rows / iteration
        const int idx = s_idx[wave * 64 + rr];       // broadcast read
        fvec4 e = cb4[idx * 16 + lrow];
        __builtin_nontemporal_store(e, &out4[(size_t)(r0 + rr) * 16 + lrow]);
    }

    // ---- loss: wave reduce -> LDS -> one atomic per block ----
    #pragma unroll
    for (int off = 32; off > 0; off >>= 1)
        lsum += __shfl_down(lsum, off, 64);
    if (lane == 0) s_red[wave] = lsum;
    __syncthreads();
    if (tid == 0) {
        float bs = 0.f;
        #pragma unroll
        for (int w = 0; w < WAVES; ++w) bs += s_red[w];
        atomicAdd(ws, bs);
        // make the loss add globally visible before the arrival counter
        asm volatile("s_waitcnt vmcnt(0)" ::: "memory");
        unsigned old = atomicAdd((unsigned*)ws + 1, 1u);
        if (old == (unsigned)(GRID - 1)) {
            float s = atomicAdd(ws, 0.0f);   // coherent read of final sum
            out[NELEM] = 1.25f * s * (1.0f / (float)NELEM);
        }
    }
}

extern "C" void kernel_launch(void* const* d_in, const int* in_sizes, int n_in,
                              void* d_out, int out_size, void* d_ws, size_t ws_size,
                              hipStream_t stream) {
    const float* z  = (const float*)d_in[0];
    const float* cb = (const float*)d_in[1];
    float* out = (float*)d_out;
    float* ws  = (float*)d_ws;   // [0]=loss accum, [1]=block counter

    hipMemsetAsync(ws, 0, 8, stream);
    vq_fused<<<GRID, 1024, 0, stream>>>(z, cb, out, ws);
}

// Round 11
// 152.094 us; speedup vs baseline: 1.1522x; 1.1522x over previous
//
#include <hip/hip_runtime.h>
#include <math.h>

// z = (64,64,64,64) fp32 -> 262144 vectors of dim 64; codebook = 1024 x 64 fp32.
constexpr int DIM  = 64;
constexpr int KCB  = 1024;
constexpr int NVEC = 262144;
constexpr long long NELEM = 16777216LL;
constexpr int WAVES   = 16;              // 1024 threads/block
constexpr int ROWS_PW = 64;              // rows per wave (4 MFMA tiles)
constexpr int GRID    = NVEC / (WAVES * ROWS_PW);  // 256 blocks = 1 per CU

typedef short bf16x8 __attribute__((ext_vector_type(8)));  // 8 bf16 = 4 VGPRs
typedef float f32x4  __attribute__((ext_vector_type(4)));

// fp32 -> bf16 round-to-nearest-even, result in low 16 bits
__device__ __forceinline__ unsigned f2bfu(float f) {
    union { float f; unsigned u; } v; v.f = f;
    return (v.u + 0x7fffu + ((v.u >> 16) & 1u)) >> 16;
}

// (u & 0xFFFFFC00) | cv in ONE VALU op (compiler can't prove cv<1024).
__device__ __forceinline__ float pack_dc(unsigned u, unsigned cv, unsigned msk) {
    unsigned r;
    asm("v_bfi_b32 %0, %1, %2, %3" : "=v"(r) : "v"(msk), "v"(u), "v"(cv));
    return __uint_as_float(r);
}

// SESSION-FINAL kernel (= round-5, the measured optimum: 71 us steady).
// Single dispatch, one block per CU, ONE barrier. Whole codebook in LDS as
// bf16(-2*cb), XOR-swizzled (16-B unit `part` of codeword `col` at slot
// col*8+((part+col)&7) => ds_read_b128 fragments <=2-way, free per m136).
// 16 waves x 64 rows (4 waves/SIMD: r7 proved 2/SIMD starves), ONE scan
// (each 4x ds_read_b128 feeds 16 MFMA), immediate consume.
// Design-space notes from r6-r10: deeper pipelining (2-deep B-prefetch +
// lag-consume) needs ~96+ VGPR but the usable budget at 1024 threads is
// hard-capped at 64 (launch_bounds(1024,4), waves_per_eu(4,4) both left
// VGPR=64 + ~50 MB scratch spill, 83 us). 512-thread variants starve TLP.
// Loss from the tracked packed min: ||z-e||^2 = ||z||^2 + (||e||^2 - 2<e,z>).
__global__ __launch_bounds__(1024, 4) void vq_fused(
        const float* __restrict__ z,
        const float* __restrict__ cb,
        float* __restrict__ out,
        float* __restrict__ ws) {

    __shared__ unsigned sB[KCB * 32];       // 128 KB swizzled bf16(-2*cb)
    __shared__ float    s_esq[KCB];         // 4 KB ||e_k||^2
    __shared__ int      s_idx[WAVES * 64];  // 4 KB per-wave argmin exchange
    __shared__ float    s_red[WAVES];       // block loss partials

    const int tid  = threadIdx.x;
    const int lane = tid & 63;
    const int wave = tid >> 6;
    const int quad = lane >> 4;
    const int lrow = lane & 15;
    const int r0   = blockIdx.x * (WAVES * ROWS_PW) + wave * ROWS_PW;

    // ---- A fragments FIRST (z is the cold per-block HBM read; its latency
    //      hides under the cb staging VALU below). A[m=lrow][k=quad*8+j],
    //      bf16(z); exact fp32 ||z||^2 partials (16 elems/lane/row-set) ----
    bf16x8 a0[4], a1[4];
    float zsq = 0.f;
    #pragma unroll
    for (int t = 0; t < 4; ++t) {
        const float* zr = z + (size_t)(r0 + t * 16 + lrow) * DIM + quad * 8;
        float4 p0 = *(const float4*)(zr);
        float4 p1 = *(const float4*)(zr + 4);
        float4 p2 = *(const float4*)(zr + 32);
        float4 p3 = *(const float4*)(zr + 36);
        zsq = fmaf(p0.x, p0.x, zsq); zsq = fmaf(p0.y, p0.y, zsq);
        zsq = fmaf(p0.z, p0.z, zsq); zsq = fmaf(p0.w, p0.w, zsq);
        zsq = fmaf(p1.x, p1.x, zsq); zsq = fmaf(p1.y, p1.y, zsq);
        zsq = fmaf(p1.z, p1.z, zsq); zsq = fmaf(p1.w, p1.w, zsq);
        zsq = fmaf(p2.x, p2.x, zsq); zsq = fmaf(p2.y, p2.y, zsq);
        zsq = fmaf(p2.z, p2.z, zsq); zsq = fmaf(p2.w, p2.w, zsq);
        zsq = fmaf(p3.x, p3.x, zsq); zsq = fmaf(p3.y, p3.y, zsq);
        zsq = fmaf(p3.z, p3.z, zsq); zsq = fmaf(p3.w, p3.w, zsq);
        a0[t][0] = (short)f2bfu(p0.x); a0[t][1] = (short)f2bfu(p0.y);
        a0[t][2] = (short)f2bfu(p0.z); a0[t][3] = (short)f2bfu(p0.w);
        a0[t][4] = (short)f2bfu(p1.x); a0[t][5] = (short)f2bfu(p1.y);
        a0[t][6] = (short)f2bfu(p1.z); a0[t][7] = (short)f2bfu(p1.w);
        a1[t][0] = (short)f2bfu(p2.x); a1[t][1] = (short)f2bfu(p2.y);
        a1[t][2] = (short)f2bfu(p2.z); a1[t][3] = (short)f2bfu(p2.w);
        a1[t][4] = (short)f2bfu(p3.x); a1[t][5] = (short)f2bfu(p3.y);
        a1[t][6] = (short)f2bfu(p3.z); a1[t][7] = (short)f2bfu(p3.w);
    }

    // ---- build B in LDS (swizzled) + esq, straight from fp32 cb ----
    // slot s = c*1024 + tid; col = s>>3, jj = s&7, part = (jj-col)&7.
    // 8 consecutive lanes hold the 8 parts of one codeword -> esq via 3 xors.
    {
        const int col_l = tid >> 3;            // 0..127 within chunk
        const int jj    = tid & 7;
        const int part  = (jj - col_l) & 7;
        const float* src = cb + col_l * DIM + part * 8;
        char* dst = (char*)sB + tid * 16;
        #pragma unroll
        for (int c = 0; c < 8; ++c) {          // chunk c: codewords c*128..
            float4 v0 = *(const float4*)(src + c * 8192);
            float4 v1 = *(const float4*)(src + c * 8192 + 4);
            float es = v0.x * v0.x;
            es = fmaf(v0.y, v0.y, es);
            es = fmaf(v0.z, v0.z, es);
            es = fmaf(v0.w, v0.w, es);
            es = fmaf(v1.x, v1.x, es);
            es = fmaf(v1.y, v1.y, es);
            es = fmaf(v1.z, v1.z, es);
            es = fmaf(v1.w, v1.w, es);
            es += __shfl_xor(es, 1, 64);
            es += __shfl_xor(es, 2, 64);
            es += __shfl_xor(es, 4, 64);
            if (jj == 0) s_esq[c * 128 + col_l] = es;
            uint4 w;
            w.x = f2bfu(-2.f * v0.x) | (f2bfu(-2.f * v0.y) << 16);
            w.y = f2bfu(-2.f * v0.z) | (f2bfu(-2.f * v0.w) << 16);
            w.z = f2bfu(-2.f * v1.x) | (f2bfu(-2.f * v1.y) << 16);
            w.w = f2bfu(-2.f * v1.z) | (f2bfu(-2.f * v1.w) << 16);
            *(uint4*)(dst + c * 16384) = w;
        }
    }

    __syncthreads();   // the ONLY staging barrier; waves free-run after this

    const int pos0 = ((quad + lrow) & 7) * 4;       // b0: part=quad   (K 0..31)
    const int pos1 = ((quad + 4 + lrow) & 7) * 4;   // b1: part=quad+4 (K 32..63)
    const int base = lrow * 32;
    const unsigned msk = 0xFFFFFC00u;

    float best[4][4];
    #pragma unroll
    for (int t = 0; t < 4; ++t)
        #pragma unroll
        for (int i = 0; i < 4; ++i) best[t][i] = INFINITY;

    // ---- single scan: 32 iters x (4 ds_read_b128 -> 16 MFMA -> min-track)
    #pragma unroll 2
    for (int ks = 0; ks < 64; ks += 2) {
        const unsigned* bpA = sB + ks * 512 + base;
        const unsigned* bpB = bpA + 512;
        bf16x8 b0A = *(const bf16x8*)(bpA + pos0);
        bf16x8 b1A = *(const bf16x8*)(bpA + pos1);
        bf16x8 b0B = *(const bf16x8*)(bpB + pos0);
        bf16x8 b1B = *(const bf16x8*)(bpB + pos1);
        const float esA = s_esq[ks * 16 + lrow];
        const float esB = s_esq[ks * 16 + 16 + lrow];
        const unsigned cvA = (unsigned)(ks * 16 + lrow);
        const unsigned cvB = cvA + 16u;
        f32x4 accA[4], accB[4];
        __builtin_amdgcn_s_setprio(1);
        #pragma unroll
        for (int t = 0; t < 4; ++t) {
            f32x4 aA = { esA, esA, esA, esA };   // C col = lane&15 -> ||e||^2
            aA = __builtin_amdgcn_mfma_f32_16x16x32_bf16(a0[t], b0A, aA, 0, 0, 0);
            aA = __builtin_amdgcn_mfma_f32_16x16x32_bf16(a1[t], b1A, aA, 0, 0, 0);
            accA[t] = aA;
            f32x4 aB = { esB, esB, esB, esB };
            aB = __builtin_amdgcn_mfma_f32_16x16x32_bf16(a0[t], b0B, aB, 0, 0, 0);
            aB = __builtin_amdgcn_mfma_f32_16x16x32_bf16(a1[t], b1B, aB, 0, 0, 0);
            accB[t] = aB;
        }
        __builtin_amdgcn_s_setprio(0);
        #pragma unroll
        for (int t = 0; t < 4; ++t)
            #pragma unroll
            for (int i = 0; i < 4; ++i) {
                float pkA = pack_dc(__float_as_uint(accA[t][i]), cvA, msk);
                float pkB = pack_dc(__float_as_uint(accB[t][i]), cvB, msk);
                best[t][i] = fminf(best[t][i], fminf(pkA, pkB));
            }
    }

    // ---- min across the 16-lane col group (butterfly) ----
    #pragma unroll
    for (int t = 0; t < 4; ++t)
        #pragma unroll
        for (int i = 0; i < 4; ++i) {
            float bs = best[t][i];
            bs = fminf(bs, __shfl_xor(bs, 1, 64));
            bs = fminf(bs, __shfl_xor(bs, 2, 64));
            bs = fminf(bs, __shfl_xor(bs, 4, 64));
            bs = fminf(bs, __shfl_xor(bs, 8, 64));
            best[t][i] = bs;
        }

    // lane lrow owns (t=lrow>>2, i=lrow&3) -> row t*16 + quad*4 + i.
    // All 16 lanes of each quad own exactly one row: no divergence.
    float mypk = best[0][0];
    #pragma unroll
    for (int t = 0; t < 4; ++t)
        #pragma unroll
        for (int i = 0; i < 4; ++i)
            if (lrow == t * 4 + i) mypk = best[t][i];

    const unsigned ub = __float_as_uint(mypk);
    s_idx[wave * 64 + (lrow >> 2) * 16 + quad * 4 + (lrow & 3)] =
        (int)(ub & 0x3FFu);
    // loss: ||z||^2 partial + (||e||^2 - 2<e,z>) of the owned row
    float lsum = zsq + __uint_as_float(ub & msk);

    // wave-local LDS exchange: same wave writes then reads; fence lgkm only.
    asm volatile("s_waitcnt lgkmcnt(0)" ::: "memory");

    // ---- epilogue: gather exact fp32 codebook rows, coalesced store ----
    const float4* cb4 = (const float4*)cb;
    float4* out4 = (float4*)out;
    #pragma unroll 4
    for (int g = 0; g < 16; ++g) {
        const int rr = g * 4 + quad;                 // 4 rows / iteration
        const int idx = s_idx[wave * 64 + rr];       // broadcast read
        float4 e = cb4[idx * 16 + lrow];
        out4[(size_t)(r0 + rr) * 16 + lrow] = e;
    }

    // ---- loss: wave reduce -> LDS -> one atomic per block ----
    #pragma unroll
    for (int off = 32; off > 0; off >>= 1)
        lsum += __shfl_down(lsum, off, 64);
    if (lane == 0) s_red[wave] = lsum;
    __syncthreads();
    if (tid == 0) {
        float bs = 0.f;
        #pragma unroll
        for (int w = 0; w < WAVES; ++w) bs += s_red[w];
        atomicAdd(ws, bs);
        // make the loss add globally visible before the arrival counter
        asm volatile("s_waitcnt vmcnt(0)" ::: "memory");
        unsigned old = atomicAdd((unsigned*)ws + 1, 1u);
        if (old == (unsigned)(GRID - 1)) {
            float s = atomicAdd(ws, 0.0f);   // coherent read of final sum
            out[NELEM] = 1.25f * s * (1.0f / (float)NELEM);
        }
    }
}

extern "C" void kernel_launch(void* const* d_in, const int* in_sizes, int n_in,
                              void* d_out, int out_size, void* d_ws, size_t ws_size,
                              hipStream_t stream) {
    const float* z  = (const float*)d_in[0];
    const float* cb = (const float*)d_in[1];
    float* out = (float*)d_out;
    float* ws  = (float*)d_ws;   // [0]=loss accum, [1]=block counter

    hipMemsetAsync(ws, 0, 8, stream);
    vq_fused<<<GRID, 1024, 0, stream>>>(z, cb, out, ws);
}

// Round 12
// 151.319 us; speedup vs baseline: 1.1581x; 1.0051x over previous
//
#include <hip/hip_runtime.h>
#include <math.h>

// z = (64,64,64,64) fp32 -> 262144 vectors of dim 64; codebook = 1024 x 64 fp32.
constexpr int DIM  = 64;
constexpr int KCB  = 1024;
constexpr int NVEC = 262144;
constexpr long long NELEM = 16777216LL;
constexpr int WAVES   = 16;              // 1024 threads/block
constexpr int ROWS_PW = 64;              // rows per wave (4 MFMA tiles)
constexpr int GRID    = NVEC / (WAVES * ROWS_PW);  // 256 blocks = 1 per CU

typedef short bf16x8 __attribute__((ext_vector_type(8)));  // 8 bf16 = 4 VGPRs
typedef float f32x4  __attribute__((ext_vector_type(4)));

// fp32 -> bf16 round-to-nearest-even, result in low 16 bits
__device__ __forceinline__ unsigned f2bfu(float f) {
    union { float f; unsigned u; } v; v.f = f;
    return (v.u + 0x7fffu + ((v.u >> 16) & 1u)) >> 16;
}

// (u & 0xFFFFFC00) | cv in ONE VALU op (compiler can't prove cv<1024).
__device__ __forceinline__ float pack_dc(unsigned u, unsigned cv, unsigned msk) {
    unsigned r;
    asm("v_bfi_b32 %0, %1, %2, %3" : "=v"(r) : "v"(msk), "v"(u), "v"(cv));
    return __uint_as_float(r);
}

// r12 = r5/r11 structure (measured optimum, 68 us steady) with ONE change:
// the scan is outer-4 x inner-unrolled-8, so all ds_read addresses become
// base-pointer + compile-time immediate offset (ds_read_b128 offset:N,
// ds_read2_b32 for esq pairs). Kills per-iteration address VALU and lets
// the scheduler hoist loads ahead within the register budget (straight-line
// code: scheduler throttles instead of spilling, unlike r9's named ranges).
// Everything else byte-identical to r11.
// Loss from the tracked packed min: ||z-e||^2 = ||z||^2 + (||e||^2 - 2<e,z>).
__global__ __launch_bounds__(1024, 4) void vq_fused(
        const float* __restrict__ z,
        const float* __restrict__ cb,
        float* __restrict__ out,
        float* __restrict__ ws) {

    __shared__ unsigned sB[KCB * 32];       // 128 KB swizzled bf16(-2*cb)
    __shared__ float    s_esq[KCB];         // 4 KB ||e_k||^2
    __shared__ int      s_idx[WAVES * 64];  // 4 KB per-wave argmin exchange
    __shared__ float    s_red[WAVES];       // block loss partials

    const int tid  = threadIdx.x;
    const int lane = tid & 63;
    const int wave = tid >> 6;
    const int quad = lane >> 4;
    const int lrow = lane & 15;
    const int r0   = blockIdx.x * (WAVES * ROWS_PW) + wave * ROWS_PW;

    // ---- A fragments FIRST (z is the cold per-block HBM read; its latency
    //      hides under the cb staging VALU below). A[m=lrow][k=quad*8+j],
    //      bf16(z); exact fp32 ||z||^2 partials (16 elems/lane/row-set) ----
    bf16x8 a0[4], a1[4];
    float zsq = 0.f;
    #pragma unroll
    for (int t = 0; t < 4; ++t) {
        const float* zr = z + (size_t)(r0 + t * 16 + lrow) * DIM + quad * 8;
        float4 p0 = *(const float4*)(zr);
        float4 p1 = *(const float4*)(zr + 4);
        float4 p2 = *(const float4*)(zr + 32);
        float4 p3 = *(const float4*)(zr + 36);
        zsq = fmaf(p0.x, p0.x, zsq); zsq = fmaf(p0.y, p0.y, zsq);
        zsq = fmaf(p0.z, p0.z, zsq); zsq = fmaf(p0.w, p0.w, zsq);
        zsq = fmaf(p1.x, p1.x, zsq); zsq = fmaf(p1.y, p1.y, zsq);
        zsq = fmaf(p1.z, p1.z, zsq); zsq = fmaf(p1.w, p1.w, zsq);
        zsq = fmaf(p2.x, p2.x, zsq); zsq = fmaf(p2.y, p2.y, zsq);
        zsq = fmaf(p2.z, p2.z, zsq); zsq = fmaf(p2.w, p2.w, zsq);
        zsq = fmaf(p3.x, p3.x, zsq); zsq = fmaf(p3.y, p3.y, zsq);
        zsq = fmaf(p3.z, p3.z, zsq); zsq = fmaf(p3.w, p3.w, zsq);
        a0[t][0] = (short)f2bfu(p0.x); a0[t][1] = (short)f2bfu(p0.y);
        a0[t][2] = (short)f2bfu(p0.z); a0[t][3] = (short)f2bfu(p0.w);
        a0[t][4] = (short)f2bfu(p1.x); a0[t][5] = (short)f2bfu(p1.y);
        a0[t][6] = (short)f2bfu(p1.z); a0[t][7] = (short)f2bfu(p1.w);
        a1[t][0] = (short)f2bfu(p2.x); a1[t][1] = (short)f2bfu(p2.y);
        a1[t][2] = (short)f2bfu(p2.z); a1[t][3] = (short)f2bfu(p2.w);
        a1[t][4] = (short)f2bfu(p3.x); a1[t][5] = (short)f2bfu(p3.y);
        a1[t][6] = (short)f2bfu(p3.z); a1[t][7] = (short)f2bfu(p3.w);
    }

    // ---- build B in LDS (swizzled) + esq, straight from fp32 cb ----
    // slot s = c*1024 + tid; col = s>>3, jj = s&7, part = (jj-col)&7.
    // 8 consecutive lanes hold the 8 parts of one codeword -> esq via 3 xors.
    {
        const int col_l = tid >> 3;            // 0..127 within chunk
        const int jj    = tid & 7;
        const int part  = (jj - col_l) & 7;
        const float* src = cb + col_l * DIM + part * 8;
        char* dst = (char*)sB + tid * 16;
        #pragma unroll
        for (int c = 0; c < 8; ++c) {          // chunk c: codewords c*128..
            float4 v0 = *(const float4*)(src + c * 8192);
            float4 v1 = *(const float4*)(src + c * 8192 + 4);
            float es = v0.x * v0.x;
            es = fmaf(v0.y, v0.y, es);
            es = fmaf(v0.z, v0.z, es);
            es = fmaf(v0.w, v0.w, es);
            es = fmaf(v1.x, v1.x, es);
            es = fmaf(v1.y, v1.y, es);
            es = fmaf(v1.z, v1.z, es);
            es = fmaf(v1.w, v1.w, es);
            es += __shfl_xor(es, 1, 64);
            es += __shfl_xor(es, 2, 64);
            es += __shfl_xor(es, 4, 64);
            if (jj == 0) s_esq[c * 128 + col_l] = es;
            uint4 w;
            w.x = f2bfu(-2.f * v0.x) | (f2bfu(-2.f * v0.y) << 16);
            w.y = f2bfu(-2.f * v0.z) | (f2bfu(-2.f * v0.w) << 16);
            w.z = f2bfu(-2.f * v1.x) | (f2bfu(-2.f * v1.y) << 16);
            w.w = f2bfu(-2.f * v1.z) | (f2bfu(-2.f * v1.w) << 16);
            *(uint4*)(dst + c * 16384) = w;
        }
    }

    __syncthreads();   // the ONLY staging barrier; waves free-run after this

    const int pos0 = ((quad + lrow) & 7) * 4;       // b0: part=quad   (K 0..31)
    const int pos1 = ((quad + 4 + lrow) & 7) * 4;   // b1: part=quad+4 (K 32..63)
    const int base = lrow * 32;
    const unsigned msk = 0xFFFFFC00u;

    float best[4][4];
    #pragma unroll
    for (int t = 0; t < 4; ++t)
        #pragma unroll
        for (int i = 0; i < 4; ++i) best[t][i] = INFINITY;

    // ---- scan: outer 4 x inner 8 pairs; all LDS offsets are immediates
    //      off 3 base pointers advanced once per outer iteration. ----
    const unsigned* pA0 = sB + base + pos0;   // part=quad   fragments
    const unsigned* pA1 = sB + base + pos1;   // part=quad+4 fragments
    const float*    pE  = s_esq + lrow;
    unsigned cv0 = (unsigned)lrow;
    for (int o = 0; o < 4; ++o) {
        #pragma unroll
        for (int u = 0; u < 8; ++u) {          // pair u: rows 64u.. (A), +16 (B)
            bf16x8 b0A = *(const bf16x8*)(pA0 + u * 1024);
            bf16x8 b1A = *(const bf16x8*)(pA1 + u * 1024);
            bf16x8 b0B = *(const bf16x8*)(pA0 + u * 1024 + 512);
            bf16x8 b1B = *(const bf16x8*)(pA1 + u * 1024 + 512);
            const float esA = pE[u * 32];
            const float esB = pE[u * 32 + 16];
            const unsigned cvA = cv0 + u * 32u;
            const unsigned cvB = cvA + 16u;
            f32x4 accA[4], accB[4];
            __builtin_amdgcn_s_setprio(1);
            #pragma unroll
            for (int t = 0; t < 4; ++t) {
                f32x4 aA = { esA, esA, esA, esA };   // C col -> ||e||^2 bcast
                aA = __builtin_amdgcn_mfma_f32_16x16x32_bf16(a0[t], b0A, aA, 0, 0, 0);
                aA = __builtin_amdgcn_mfma_f32_16x16x32_bf16(a1[t], b1A, aA, 0, 0, 0);
                accA[t] = aA;
                f32x4 aB = { esB, esB, esB, esB };
                aB = __builtin_amdgcn_mfma_f32_16x16x32_bf16(a0[t], b0B, aB, 0, 0, 0);
                aB = __builtin_amdgcn_mfma_f32_16x16x32_bf16(a1[t], b1B, aB, 0, 0, 0);
                accB[t] = aB;
            }
            __builtin_amdgcn_s_setprio(0);
            #pragma unroll
            for (int t = 0; t < 4; ++t)
                #pragma unroll
                for (int i = 0; i < 4; ++i) {
                    float pkA = pack_dc(__float_as_uint(accA[t][i]), cvA, msk);
                    float pkB = pack_dc(__float_as_uint(accB[t][i]), cvB, msk);
                    best[t][i] = fminf(best[t][i], fminf(pkA, pkB));
                }
        }
        pA0 += 8192; pA1 += 8192; pE += 256; cv0 += 256u;
    }

    // ---- min across the 16-lane col group (butterfly) ----
    #pragma unroll
    for (int t = 0; t < 4; ++t)
        #pragma unroll
        for (int i = 0; i < 4; ++i) {
            float bs = best[t][i];
            bs = fminf(bs, __shfl_xor(bs, 1, 64));
            bs = fminf(bs, __shfl_xor(bs, 2, 64));
            bs = fminf(bs, __shfl_xor(bs, 4, 64));
            bs = fminf(bs, __shfl_xor(bs, 8, 64));
            best[t][i] = bs;
        }

    // lane lrow owns (t=lrow>>2, i=lrow&3) -> row t*16 + quad*4 + i.
    // All 16 lanes of each quad own exactly one row: no divergence.
    float mypk = best[0][0];
    #pragma unroll
    for (int t = 0; t < 4; ++t)
        #pragma unroll
        for (int i = 0; i < 4; ++i)
            if (lrow == t * 4 + i) mypk = best[t][i];

    const unsigned ub = __float_as_uint(mypk);
    s_idx[wave * 64 + (lrow >> 2) * 16 + quad * 4 + (lrow & 3)] =
        (int)(ub & 0x3FFu);
    // loss: ||z||^2 partial + (||e||^2 - 2<e,z>) of the owned row
    float lsum = zsq + __uint_as_float(ub & msk);

    // wave-local LDS exchange: same wave writes then reads; fence lgkm only.
    asm volatile("s_waitcnt lgkmcnt(0)" ::: "memory");

    // ---- epilogue: gather exact fp32 codebook rows, coalesced store ----
    const float4* cb4 = (const float4*)cb;
    float4* out4 = (float4*)out;
    #pragma unroll 4
    for (int g = 0; g < 16; ++g) {
        const int rr = g * 4 + quad;                 // 4 rows / iteration
        const int idx = s_idx[wave * 64 + rr];       // broadcast read
        float4 e = cb4[idx * 16 + lrow];
        out4[(size_t)(r0 + rr) * 16 + lrow] = e;
    }

    // ---- loss: wave reduce -> LDS -> one atomic per block ----
    #pragma unroll
    for (int off = 32; off > 0; off >>= 1)
        lsum += __shfl_down(lsum, off, 64);
    if (lane == 0) s_red[wave] = lsum;
    __syncthreads();
    if (tid == 0) {
        float bs = 0.f;
        #pragma unroll
        for (int w = 0; w < WAVES; ++w) bs += s_red[w];
        atomicAdd(ws, bs);
        // make the loss add globally visible before the arrival counter
        asm volatile("s_waitcnt vmcnt(0)" ::: "memory");
        unsigned old = atomicAdd((unsigned*)ws + 1, 1u);
        if (old == (unsigned)(GRID - 1)) {
            float s = atomicAdd(ws, 0.0f);   // coherent read of final sum
            out[NELEM] = 1.25f * s * (1.0f / (float)NELEM);
        }
    }
}

extern "C" void kernel_launch(void* const* d_in, const int* in_sizes, int n_in,
                              void* d_out, int out_size, void* d_ws, size_t ws_size,
                              hipStream_t stream) {
    const float* z  = (const float*)d_in[0];
    const float* cb = (const float*)d_in[1];
    float* out = (float*)d_out;
    float* ws  = (float*)d_ws;   // [0]=loss accum, [1]=block counter

    hipMemsetAsync(ws, 0, 8, stream);
    vq_fused<<<GRID, 1024, 0, stream>>>(z, cb, out, ws);
}